// Round 7
// baseline (303.237 us; speedup 1.0000x reference)
//
#include <hip/hip_runtime.h>
#include <cmath>

// Problem constants
#define BATCH 8
#define HF 512
#define WF 512
#define HS 256
#define WS 256
#define PLANE_S (HS * WS)   // 65536
#define PLANE_F (HF * WF)   // 262144

#define NMIND_BLOCKS 2048   // 16x16 tiles (32x32 output each) x 8 batches
#define NREG_BLOCKS  512    // 8x8 tiles (32x32 pooled each) x 8 batches
#define TOTAL_BLOCKS (NMIND_BLOCKS + NREG_BLOCKS)

// Workspace layout (bytes); hist+done zeroed by one hipMemsetAsync
#define OFF_HIST  0                              // 8*256 u32
#define OFF_DONE  8192                           // 1 u32 done-counter
#define OFF_PMIND 8256                           // 2048 doubles
#define OFF_PGRAD (OFF_PMIND + NMIND_BLOCKS * 8) // 512 doubles
#define OFF_PLAP  (OFF_PGRAD + NREG_BLOCKS * 8)  // 512 doubles

// mind-role geometry (32x32 output tile)
#define IMG_R 23   // pooled img patch (halo: +3 left/top, +19 span)
#define IMG_S 25
#define T_R 20
#define T_S 21
#define V_R 18     // diff/var patch
#define V_S 19
#define VP  (V_R * V_S)   // 342, diff plane stride (in float2 units for packed pairs)

// reg-role geometry (32x32 pooled tile)
#define RP 34
#define RS 35

__device__ __forceinline__ int clampi(int v, int lo, int hi) {
    return v < lo ? lo : (v > hi ? hi : v);
}

__device__ __forceinline__ int bin_of(float x) {
    float v = (x + 1.0f) * 0.5f;
    v = fminf(fmaxf(v, 0.001f), 0.999f);
    float t = v * 16.0f;            // exact (power-of-2 scale)
    float ft = floorf(t);
    int c = (int)ft + ((t > ft) ? 1 : 0);   // searchsorted-left count of grid < v
    int b = c - 1;
    return b < 0 ? 0 : (b > 15 ? 15 : b);
}

// ONE dispatch. Blocks 0..2047: MIND role. Blocks 2048..2559: reg role.
// Last block to finish (device-scope counter) computes NMI + final combine.
__global__ __launch_bounds__(256, 6) void fused_all_kernel(
    const float* __restrict__ fixed, const float* __restrict__ moved,
    const float* __restrict__ flow,
    unsigned* __restrict__ hist, unsigned* __restrict__ done,
    double* __restrict__ pmind, double* __restrict__ pgrad, double* __restrict__ plap,
    float* __restrict__ out)
{
    __shared__ float S[4570];       // 18.3 KB, shared by roles and finisher
    __shared__ unsigned lh[256];
    __shared__ float red[256];
    __shared__ unsigned last_flag;
    __shared__ float nmi_acc_s;
    int tid = threadIdx.x;

    if (blockIdx.x < NMIND_BLOCKS) {
        // ---------------- MIND role ----------------
        int mb = blockIdx.x;                 // 0..2047
        int b = mb >> 8, rem = mb & 255;
        int ty = rem >> 4, tx = rem & 15;
        const float FS = (float)(255.0 / 511.0);
        int Xb = tx * 32, Yb = ty * 32;
        int dbx = (int)((float)Xb * FS);     // min x0 over tile (fp32 mult is monotone)
        int dby = (int)((float)Yb * FS);
        int ibx = dbx - 3, iby = dby - 3;

        float* imgF = S;                     // 23*25 = 575
        float* imgM = S + 575;               // 575
        float* varF = S + 1150;              // 18*19 = 342
        float* varM = S + 1492;              // 342
        float2* diff2 = (float2*)(S + 1834); // 4 channel-pairs * 342 float2 = 2736 floats
        float* tF   = S + 1834;              // 20*21 = 420 (dead before diff written)
        float* tM   = tF + T_R * T_S;        // 420

        lh[tid] = 0u;
        __syncthreads();

        // ---- stage pooled F/M patches (clamp = edge-pad) + ::2,::2 histogram samples
        const float* fb = fixed + (size_t)b * PLANE_F;
        const float* mbp = moved + (size_t)b * PLANE_F;
        int oy0 = ty * 16, ox0 = tx * 16;    // owned pooled box (exact cover of 256x256)
        for (int i = tid; i < IMG_R * IMG_R; i += 256) {
            int r = i / IMG_R, c = i - r * IMG_R;
            int gy = iby + r, gx = ibx + c;
            int cy = clampi(gy, 0, HS - 1), cx = clampi(gx, 0, WS - 1);
            const float* fp = fb + (size_t)(cy * 2) * WF + (size_t)(cx * 2);
            const float* mp = mbp + (size_t)(cy * 2) * WF + (size_t)(cx * 2);
            float2 f0 = *(const float2*)fp;
            float2 f1 = *(const float2*)(fp + WF);
            float2 m0 = *(const float2*)mp;
            float2 m1 = *(const float2*)(mp + WF);
            imgF[r * IMG_S + c] = (f0.x + f0.y + f1.x + f1.y) * 0.25f;
            imgM[r * IMG_S + c] = (m0.x + m0.y + m1.x + m1.y) * 0.25f;
            if ((unsigned)(gy - oy0) < 16u && (unsigned)(gx - ox0) < 16u) {
                atomicAdd(&lh[bin_of(f0.x) * 16 + bin_of(m0.x)], 1u);
            }
        }
        __syncthreads();
        { // u32 global atomics (fire-and-forget); hist zeroed by host memset
            unsigned v = lh[tid];
            if (v) atomicAdd(&hist[b * 256 + tid], v);
        }

        // ---- t = (img[q] - boxmean(img[q-2..q]))^2   [reference pad/slice quirk]
        for (int i = tid; i < T_R * T_R; i += 256) {
            int r = i / T_R, c = i - r * T_R;
            float sF = 0.f, sM = 0.f;
            #pragma unroll
            for (int dy = 0; dy < 3; dy++)
                #pragma unroll
                for (int dx = 0; dx < 3; dx++) {
                    sF += imgF[(r + dy) * IMG_S + c + dx];
                    sM += imgM[(r + dy) * IMG_S + c + dx];
                }
            float dF = imgF[(r + 2) * IMG_S + c + 2] - sF / 9.0f;
            float dM = imgM[(r + 2) * IMG_S + c + 2] - sM / 9.0f;
            tF[r * T_S + c] = dF * dF;
            tM[r * T_S + c] = dM * dM;
        }
        __syncthreads();

        // ---- var = max(box3x3(t)/9, 1e-4); keep in regs (t aliased by diff)
        float vFl[2], vMl[2];
        int vi[2];
        #pragma unroll
        for (int p = 0; p < 2; p++) {
            int i = tid + p * 256;
            vi[p] = -1;
            if (i < V_R * V_R) {
                int r = i / V_R, c = i - r * V_R;
                float sF = 0.f, sM = 0.f;
                #pragma unroll
                for (int dy = 0; dy < 3; dy++)
                    #pragma unroll
                    for (int dx = 0; dx < 3; dx++) {
                        sF += tF[(r + dy) * T_S + c + dx];
                        sM += tM[(r + dy) * T_S + c + dx];
                    }
                vFl[p] = fmaxf(sF / 9.0f, 1e-4f);
                vMl[p] = fmaxf(sM / 9.0f, 1e-4f);
                vi[p] = r * V_S + c;
            }
        }
        __syncthreads();
        #pragma unroll
        for (int p = 0; p < 2; p++) if (vi[p] >= 0) { varF[vi[p]] = vFl[p]; varM[vi[p]] = vMl[p]; }
        __syncthreads();

        // ---- MIND + diff, channel-PAIR packed planes (float2, odd row stride): conflict-free
        for (int i = tid; i < V_R * V_R; i += 256) {
            int r = i / V_R, c = i - r * V_R;
            float cF = imgF[(r + 3) * IMG_S + c + 3];
            float cM = imgM[(r + 3) * IMG_S + c + 3];
            float dF2 = 2.f * varF[r * V_S + c] + 1e-6f;
            float dM2 = 2.f * varM[r * V_S + c] + 1e-6f;
            float eF[8], eM[8];
            float sF = 0.f, sM = 0.f;
            int ch = 0;
            #pragma unroll
            for (int ii = -1; ii <= 1; ii++) {
                #pragma unroll
                for (int jj = -1; jj <= 1; jj++) {
                    if (ii == 0 && jj == 0) continue;
                    float aF = cF - imgF[(r + 3 + 2 * jj) * IMG_S + (c + 3 + 2 * ii)];
                    float aM = cM - imgM[(r + 3 + 2 * jj) * IMG_S + (c + 3 + 2 * ii)];
                    float qF = fminf(aF * aF / dF2, 50.f);
                    float qM = fminf(aM * aM / dM2, 50.f);
                    float vF_ = __expf(-qF), vM_ = __expf(-qM);
                    eF[ch] = vF_; eM[ch] = vM_;
                    sF += vF_; sM += vM_;
                    ch++;
                }
            }
            float wF = 1.f / (sF + 1e-8f);
            float wM = 1.f / (sM + 1e-8f);
            int base = r * V_S + c;
            #pragma unroll
            for (int q2 = 0; q2 < 4; q2++) {
                float2 d;
                d.x = eF[2 * q2]     * wF - eM[2 * q2]     * wM;
                d.y = eF[2 * q2 + 1] * wF - eM[2 * q2 + 1] * wM;
                diff2[q2 * VP + base] = d;
            }
        }
        __syncthreads();

        // ---- bilinear align-corners upsample + sum|.| (exact reference association)
        float local = 0.f;
        for (int k = tid; k < 32 * 32; k += 256) {
            int dy = k >> 5, dx = k & 31;
            float py = (float)(Yb + dy) * FS;
            int y0 = (int)py; if (y0 > HS - 2) y0 = HS - 2;
            float fy = py - (float)y0;
            float px = (float)(Xb + dx) * FS;
            int x0 = (int)px; if (x0 > WS - 2) x0 = WS - 2;
            float fx = px - (float)x0;
            float omfy = 1.f - fy, omfx = 1.f - fx;
            int base = (y0 - dby) * V_S + (x0 - dbx);
            #pragma unroll
            for (int q2 = 0; q2 < 4; q2++) {
                const float2* pq = diff2 + q2 * VP + base;
                float2 p00 = pq[0], p01 = pq[1];
                float2 p10 = pq[V_S], p11 = pq[V_S + 1];
                float ax = p00.x * omfy + p10.x * fy;
                float bx = p01.x * omfy + p11.x * fy;
                local += fabsf(ax * omfx + bx * fx);
                float ay = p00.y * omfy + p10.y * fy;
                float by = p01.y * omfy + p11.y * fy;
                local += fabsf(ay * omfx + by * fx);
            }
        }
        red[tid] = local;
        __syncthreads();
        for (int s = 128; s > 0; s >>= 1) { if (tid < s) red[tid] += red[tid + s]; __syncthreads(); }
        if (tid == 0) pmind[mb] = (double)red[0];
    } else {
        // ---------------- reg role ----------------
        int rb = blockIdx.x - NMIND_BLOCKS;     // 0..511
        int b = rb >> 6, rem = rb & 63;
        int tyr = rem >> 3, txr = rem & 7;
        int y0p = tyr * 32, x0p = txr * 32;
        float* U = S;                 // 34*35 = 1190
        float* V = S + RP * RS;       // 1190
        const float* ur = flow + (size_t)(b * 2) * PLANE_F;
        const float* vr = ur + PLANE_F;
        for (int i = tid; i < RP * RP; i += 256) {
            int r = i / RP, c = i - r * RP;
            int gy = clampi(y0p - 1 + r, 0, HS - 1);
            int gx = clampi(x0p - 1 + c, 0, WS - 1);
            const float* uu = ur + (size_t)(gy * 2) * WF + (size_t)(gx * 2);
            const float* vv = vr + (size_t)(gy * 2) * WF + (size_t)(gx * 2);
            float2 u0 = *(const float2*)uu, u1 = *(const float2*)(uu + WF);
            float2 v0 = *(const float2*)vv, v1 = *(const float2*)(vv + WF);
            U[r * RS + c] = (u0.x + u0.y + u1.x + u1.y) * 0.25f;
            V[r * RS + c] = (v0.x + v0.y + v1.x + v1.y) * 0.25f;
        }
        __syncthreads();
        float g = 0.f, l = 0.f;
        for (int k = tid; k < 32 * 32; k += 256) {
            int y = k >> 5, x = k & 31;
            const float* u0 = &U[y * RS + x];
            const float* v0 = &V[y * RS + x];
            float a00 = u0[0],      a01 = u0[1],          a02 = u0[2];
            float a10 = u0[RS],     a11 = u0[RS + 1],     a12 = u0[RS + 2];
            float a20 = u0[2 * RS], a21 = u0[2 * RS + 1], a22 = u0[2 * RS + 2];
            float c00 = v0[0],      c01 = v0[1],          c02 = v0[2];
            float c10 = v0[RS],     c11 = v0[RS + 1],     c12 = v0[RS + 2];
            float c20 = v0[2 * RS], c21 = v0[2 * RS + 1], c22 = v0[2 * RS + 2];
            float gxu = (a02 - a00) + 2.f * (a12 - a10) + (a22 - a20);
            float gyu = (a20 - a00) + 2.f * (a21 - a01) + (a22 - a02);
            float gxv = (c02 - c00) + 2.f * (c12 - c10) + (c22 - c20);
            float gyv = (c20 - c00) + 2.f * (c21 - c01) + (c22 - c02);
            float lpu = a01 + a10 - 4.f * a11 + a12 + a21;
            float lpv = c01 + c10 - 4.f * c11 + c12 + c21;
            float grad = gxu * gxu + gyu * gyu + gxv * gxv + gyv * gyv;
            float lap = lpu * lpu + lpv * lpv;
            g += fminf(grad, 100.f);
            l += fminf(lap, 100.f);
        }
        red[tid] = g;
        __syncthreads();
        for (int s = 128; s > 0; s >>= 1) { if (tid < s) red[tid] += red[tid + s]; __syncthreads(); }
        if (tid == 0) pgrad[rb] = (double)red[0];
        __syncthreads();
        red[tid] = l;
        __syncthreads();
        for (int s = 128; s > 0; s >>= 1) { if (tid < s) red[tid] += red[tid + s]; __syncthreads(); }
        if (tid == 0) plap[rb] = (double)red[0];
    }

    // ---------------- signal completion; last block computes NMI + final ----------------
    __threadfence();   // device-scope release of this block's stores/atomics
    if (tid == 0) {
        unsigned prev = __hip_atomic_fetch_add(done, 1u, __ATOMIC_ACQ_REL, __HIP_MEMORY_SCOPE_AGENT);
        last_flag = (prev == TOTAL_BLOCKS - 1) ? 1u : 0u;
        if (tid == 0 && last_flag) nmi_acc_s = 0.f;
    }
    __syncthreads();
    if (!last_flag) return;
    __threadfence();   // acquire

    // finisher scratch aliased into S (role data is dead)
    float* p    = S;                 // 256
    float* red2 = S + 256;           // 256
    float* xh   = S + 512;           // 16
    float* yh   = S + 528;           // 16
    double* redd = (double*)(S + 544); // 256 doubles (8B-aligned: 544*4 % 8 == 0)
    int t = tid;

    for (int b = 0; b < BATCH; b++) {
        unsigned hv = __hip_atomic_load(&hist[b * 256 + t], __ATOMIC_RELAXED, __HIP_MEMORY_SCOPE_AGENT);
        float pv = (float)hv / 65536.0f;  // sum+1e-10 == 65536 in fp32
        p[t] = pv;
        __syncthreads();
        if (t < 16) {
            float s = 0.f;
            for (int j = 0; j < 16; j++) s += p[t * 16 + j];
            xh[t] = s;
        } else if (t < 32) {
            int j = t - 16;
            float s = 0.f;
            for (int i = 0; i < 16; i++) s += p[i * 16 + j];
            yh[j] = s;
        }
        __syncthreads();
        const float eps = 1e-5f;
        int i = t >> 4, j = t & 15;
        float h = pv + eps;
        float mi_term = h * (logf(h) - logf((xh[i] + eps) * (yh[j] + eps)));
        red2[t] = mi_term;
        __syncthreads();
        for (int s = 128; s > 0; s >>= 1) { if (t < s) red2[t] += red2[t + s]; __syncthreads(); }
        float mi = red2[0];
        __syncthreads();
        float e_term = 0.f;
        if (t < 16) { float xe = xh[t] + eps; e_term = -xe * logf(xe); }
        else if (t < 32) { float ye = yh[t - 16] + eps; e_term = -ye * logf(ye); }
        red2[t] = e_term;
        __syncthreads();
        for (int s = 128; s > 0; s >>= 1) { if (t < s) red2[t] += red2[t + s]; __syncthreads(); }
        if (t == 0) {
            float se = red2[0];  // hx + hy
            float nmi = (se < 1e-10f) ? 0.f : 2.f * mi / se;
            nmi_acc_s += fminf(fmaxf(nmi, -1.f), 1.f);
        }
        __syncthreads();
    }

    double sm = 0.0;
    for (int i = t; i < NMIND_BLOCKS; i += 256)
        sm += __hip_atomic_load(&pmind[i], __ATOMIC_RELAXED, __HIP_MEMORY_SCOPE_AGENT);
    double sg = 0.0, sl = 0.0;
    for (int i = t; i < NREG_BLOCKS; i += 256) {
        sg += __hip_atomic_load(&pgrad[i], __ATOMIC_RELAXED, __HIP_MEMORY_SCOPE_AGENT);
        sl += __hip_atomic_load(&plap[i],  __ATOMIC_RELAXED, __HIP_MEMORY_SCOPE_AGENT);
    }
    redd[t] = sm;
    __syncthreads();
    for (int s = 128; s > 0; s >>= 1) { if (t < s) redd[t] += redd[t + s]; __syncthreads(); }
    double mind_sum = redd[0];
    __syncthreads();
    redd[t] = sg;
    __syncthreads();
    for (int s = 128; s > 0; s >>= 1) { if (t < s) redd[t] += redd[t + s]; __syncthreads(); }
    double grad_sum = redd[0];
    __syncthreads();
    redd[t] = sl;
    __syncthreads();
    for (int s = 128; s > 0; s >>= 1) { if (t < s) redd[t] += redd[t + s]; __syncthreads(); }
    double lap_sum = redd[0];
    if (t == 0) {
        float s = nmi_acc_s / (float)BATCH;
        s = fminf(fmaxf(s, -1.f), 1.f);
        double mi_loss = -(double)s;
        double mind_mean = mind_sum / (64.0 * (double)PLANE_F);
        double reg = grad_sum / (double)(BATCH * PLANE_S) + lap_sum / (double)(BATCH * PLANE_S);
        out[0] = (float)(mi_loss + 5.0 * mind_mean + 0.1 * reg);
    }
}

extern "C" void kernel_launch(void* const* d_in, const int* in_sizes, int n_in,
                              void* d_out, int out_size, void* d_ws, size_t ws_size,
                              hipStream_t stream) {
    const float* fixed = (const float*)d_in[0];
    const float* moved = (const float*)d_in[1];
    const float* flow  = (const float*)d_in[2];
    float* out = (float*)d_out;
    char* ws = (char*)d_ws;

    unsigned* hist  = (unsigned*)(ws + OFF_HIST);
    unsigned* done  = (unsigned*)(ws + OFF_DONE);
    double*   pmind = (double*)(ws + OFF_PMIND);
    double*   pgrad = (double*)(ws + OFF_PGRAD);
    double*   plap  = (double*)(ws + OFF_PLAP);

    // zero hist + done counter (capturable async memset; replaces init_kernel)
    hipMemsetAsync(ws + OFF_HIST, 0, OFF_PMIND, stream);

    fused_all_kernel<<<TOTAL_BLOCKS, 256, 0, stream>>>(
        fixed, moved, flow, hist, done, pmind, pgrad, plap, out);
}

// Round 8
// 180.235 us; speedup vs baseline: 1.6825x; 1.6825x over previous
//
#include <hip/hip_runtime.h>
#include <cmath>

// Problem constants
#define BATCH 8
#define HF 512
#define WF 512
#define HS 256
#define WS 256
#define PLANE_S (HS * WS)   // 65536
#define PLANE_F (HF * WF)   // 262144

#define NMIND_BLOCKS 2048   // 16x16 tiles (32x32 output each) x 8 batches
#define NREG_BLOCKS  512    // 8x8 tiles (32x32 pooled each) x 8 batches
#define TOTAL_BLOCKS (NMIND_BLOCKS + NREG_BLOCKS)
#define MB (1048576)

// Workspace layout (bytes) — every byte written before read, no init/memset needed
#define OFF_HISTP 0                              // 2048 blocks * 256 u32 = 2 MB (plain stores)
#define OFF_PMIND (2 * MB)                       // 2048 doubles
#define OFF_PGRAD (OFF_PMIND + NMIND_BLOCKS * 8) // 512 doubles
#define OFF_PLAP  (OFF_PGRAD + NREG_BLOCKS * 8)  // 512 doubles

// mind-role geometry (32x32 output tile)
#define IMG_R 23   // pooled img patch (halo: +3 left/top, +19 span)
#define IMG_S 25
#define T_R 20
#define T_S 21
#define V_R 18     // diff/var patch
#define V_S 19
#define VP  (V_R * V_S)   // 342, diff plane stride (float2 units for packed pairs)

// reg-role geometry (32x32 pooled tile)
#define RP 34
#define RS 35

__device__ __forceinline__ int clampi(int v, int lo, int hi) {
    return v < lo ? lo : (v > hi ? hi : v);
}

__device__ __forceinline__ int bin_of(float x) {
    float v = (x + 1.0f) * 0.5f;
    v = fminf(fmaxf(v, 0.001f), 0.999f);
    float t = v * 16.0f;            // exact (power-of-2 scale)
    float ft = floorf(t);
    int c = (int)ft + ((t > ft) ? 1 : 0);   // searchsorted-left count of grid < v
    int b = c - 1;
    return b < 0 ? 0 : (b > 15 ? 15 : b);
}

// ONE compute dispatch. Blocks 0..2047: MIND role. Blocks 2048..2559: reg role.
// NO device-scope fences/atomics anywhere (per-XCD L2 writeback per block was the
// R6 disaster: 240 µs). Kernel boundary is the coherence point.
__global__ __launch_bounds__(256, 6) void fused_main_kernel(
    const float* __restrict__ fixed, const float* __restrict__ moved,
    const float* __restrict__ flow,
    unsigned* __restrict__ hist_part,
    double* __restrict__ pmind, double* __restrict__ pgrad, double* __restrict__ plap)
{
    __shared__ float S[4570];       // 18.3 KB, shared by both roles
    __shared__ unsigned lh[256];
    __shared__ float red[256];
    int tid = threadIdx.x;

    if (blockIdx.x < NMIND_BLOCKS) {
        // ---------------- MIND role ----------------
        int mb = blockIdx.x;                 // 0..2047
        int b = mb >> 8, rem = mb & 255;
        int ty = rem >> 4, tx = rem & 15;
        const float FS = (float)(255.0 / 511.0);
        int Xb = tx * 32, Yb = ty * 32;
        int dbx = (int)((float)Xb * FS);     // min x0 over tile (fp32 mult is monotone)
        int dby = (int)((float)Yb * FS);
        int ibx = dbx - 3, iby = dby - 3;

        float* imgF = S;                     // 23*25 = 575
        float* imgM = S + 575;               // 575
        float* varF = S + 1150;              // 18*19 = 342
        float* varM = S + 1492;              // 342
        float2* diff2 = (float2*)(S + 1834); // 4 channel-pairs * 342 float2 = 2736 floats
        float* tF   = S + 1834;              // 20*21 = 420 (dead before diff written)
        float* tM   = tF + T_R * T_S;        // 420

        lh[tid] = 0u;
        __syncthreads();

        // ---- stage pooled F/M patches (clamp = edge-pad) + ::2,::2 histogram samples
        const float* fb = fixed + (size_t)b * PLANE_F;
        const float* mbp = moved + (size_t)b * PLANE_F;
        int oy0 = ty * 16, ox0 = tx * 16;    // owned pooled box (exact cover of 256x256)
        for (int i = tid; i < IMG_R * IMG_R; i += 256) {
            int r = i / IMG_R, c = i - r * IMG_R;
            int gy = iby + r, gx = ibx + c;
            int cy = clampi(gy, 0, HS - 1), cx = clampi(gx, 0, WS - 1);
            const float* fp = fb + (size_t)(cy * 2) * WF + (size_t)(cx * 2);
            const float* mp = mbp + (size_t)(cy * 2) * WF + (size_t)(cx * 2);
            float2 f0 = *(const float2*)fp;
            float2 f1 = *(const float2*)(fp + WF);
            float2 m0 = *(const float2*)mp;
            float2 m1 = *(const float2*)(mp + WF);
            imgF[r * IMG_S + c] = (f0.x + f0.y + f1.x + f1.y) * 0.25f;
            imgM[r * IMG_S + c] = (m0.x + m0.y + m1.x + m1.y) * 0.25f;
            if ((unsigned)(gy - oy0) < 16u && (unsigned)(gx - ox0) < 16u) {
                atomicAdd(&lh[bin_of(f0.x) * 16 + bin_of(m0.x)], 1u);   // LDS atomic only
            }
        }
        __syncthreads();
        // per-block histogram partial: plain coalesced store, no init dependency
        hist_part[(size_t)mb * 256 + tid] = lh[tid];

        // ---- t = (img[q] - boxmean(img[q-2..q]))^2   [reference pad/slice quirk]
        for (int i = tid; i < T_R * T_R; i += 256) {
            int r = i / T_R, c = i - r * T_R;
            float sF = 0.f, sM = 0.f;
            #pragma unroll
            for (int dy = 0; dy < 3; dy++)
                #pragma unroll
                for (int dx = 0; dx < 3; dx++) {
                    sF += imgF[(r + dy) * IMG_S + c + dx];
                    sM += imgM[(r + dy) * IMG_S + c + dx];
                }
            float dF = imgF[(r + 2) * IMG_S + c + 2] - sF / 9.0f;
            float dM = imgM[(r + 2) * IMG_S + c + 2] - sM / 9.0f;
            tF[r * T_S + c] = dF * dF;
            tM[r * T_S + c] = dM * dM;
        }
        __syncthreads();

        // ---- var = max(box3x3(t)/9, 1e-4); keep in regs (t aliased by diff)
        float vFl[2], vMl[2];
        int vi[2];
        #pragma unroll
        for (int p = 0; p < 2; p++) {
            int i = tid + p * 256;
            vi[p] = -1;
            if (i < V_R * V_R) {
                int r = i / V_R, c = i - r * V_R;
                float sF = 0.f, sM = 0.f;
                #pragma unroll
                for (int dy = 0; dy < 3; dy++)
                    #pragma unroll
                    for (int dx = 0; dx < 3; dx++) {
                        sF += tF[(r + dy) * T_S + c + dx];
                        sM += tM[(r + dy) * T_S + c + dx];
                    }
                vFl[p] = fmaxf(sF / 9.0f, 1e-4f);
                vMl[p] = fmaxf(sM / 9.0f, 1e-4f);
                vi[p] = r * V_S + c;
            }
        }
        __syncthreads();
        #pragma unroll
        for (int p = 0; p < 2; p++) if (vi[p] >= 0) { varF[vi[p]] = vFl[p]; varM[vi[p]] = vMl[p]; }
        __syncthreads();

        // ---- MIND + diff, channel-PAIR packed planes (float2): conflict-free b64
        for (int i = tid; i < V_R * V_R; i += 256) {
            int r = i / V_R, c = i - r * V_R;
            float cF = imgF[(r + 3) * IMG_S + c + 3];
            float cM = imgM[(r + 3) * IMG_S + c + 3];
            float dF2 = 2.f * varF[r * V_S + c] + 1e-6f;
            float dM2 = 2.f * varM[r * V_S + c] + 1e-6f;
            float eF[8], eM[8];
            float sF = 0.f, sM = 0.f;
            int ch = 0;
            #pragma unroll
            for (int ii = -1; ii <= 1; ii++) {
                #pragma unroll
                for (int jj = -1; jj <= 1; jj++) {
                    if (ii == 0 && jj == 0) continue;
                    float aF = cF - imgF[(r + 3 + 2 * jj) * IMG_S + (c + 3 + 2 * ii)];
                    float aM = cM - imgM[(r + 3 + 2 * jj) * IMG_S + (c + 3 + 2 * ii)];
                    float qF = fminf(aF * aF / dF2, 50.f);
                    float qM = fminf(aM * aM / dM2, 50.f);
                    float vF_ = __expf(-qF), vM_ = __expf(-qM);
                    eF[ch] = vF_; eM[ch] = vM_;
                    sF += vF_; sM += vM_;
                    ch++;
                }
            }
            float wF = 1.f / (sF + 1e-8f);
            float wM = 1.f / (sM + 1e-8f);
            int base = r * V_S + c;
            #pragma unroll
            for (int q2 = 0; q2 < 4; q2++) {
                float2 d;
                d.x = eF[2 * q2]     * wF - eM[2 * q2]     * wM;
                d.y = eF[2 * q2 + 1] * wF - eM[2 * q2 + 1] * wM;
                diff2[q2 * VP + base] = d;
            }
        }
        __syncthreads();

        // ---- bilinear align-corners upsample + sum|.| (exact reference association)
        float local = 0.f;
        for (int k = tid; k < 32 * 32; k += 256) {
            int dy = k >> 5, dx = k & 31;
            float py = (float)(Yb + dy) * FS;
            int y0 = (int)py; if (y0 > HS - 2) y0 = HS - 2;
            float fy = py - (float)y0;
            float px = (float)(Xb + dx) * FS;
            int x0 = (int)px; if (x0 > WS - 2) x0 = WS - 2;
            float fx = px - (float)x0;
            float omfy = 1.f - fy, omfx = 1.f - fx;
            int base = (y0 - dby) * V_S + (x0 - dbx);
            #pragma unroll
            for (int q2 = 0; q2 < 4; q2++) {
                const float2* pq = diff2 + q2 * VP + base;
                float2 p00 = pq[0], p01 = pq[1];
                float2 p10 = pq[V_S], p11 = pq[V_S + 1];
                float ax = p00.x * omfy + p10.x * fy;
                float bx = p01.x * omfy + p11.x * fy;
                local += fabsf(ax * omfx + bx * fx);
                float ay = p00.y * omfy + p10.y * fy;
                float by = p01.y * omfy + p11.y * fy;
                local += fabsf(ay * omfx + by * fx);
            }
        }
        red[tid] = local;
        __syncthreads();
        for (int s = 128; s > 0; s >>= 1) { if (tid < s) red[tid] += red[tid + s]; __syncthreads(); }
        if (tid == 0) pmind[mb] = (double)red[0];
    } else {
        // ---------------- reg role ----------------
        int rb = blockIdx.x - NMIND_BLOCKS;     // 0..511
        int b = rb >> 6, rem = rb & 63;
        int tyr = rem >> 3, txr = rem & 7;
        int y0p = tyr * 32, x0p = txr * 32;
        float* U = S;                 // 34*35 = 1190
        float* V = S + RP * RS;       // 1190
        const float* ur = flow + (size_t)(b * 2) * PLANE_F;
        const float* vr = ur + PLANE_F;
        for (int i = tid; i < RP * RP; i += 256) {
            int r = i / RP, c = i - r * RP;
            int gy = clampi(y0p - 1 + r, 0, HS - 1);
            int gx = clampi(x0p - 1 + c, 0, WS - 1);
            const float* uu = ur + (size_t)(gy * 2) * WF + (size_t)(gx * 2);
            const float* vv = vr + (size_t)(gy * 2) * WF + (size_t)(gx * 2);
            float2 u0 = *(const float2*)uu, u1 = *(const float2*)(uu + WF);
            float2 v0 = *(const float2*)vv, v1 = *(const float2*)(vv + WF);
            U[r * RS + c] = (u0.x + u0.y + u1.x + u1.y) * 0.25f;
            V[r * RS + c] = (v0.x + v0.y + v1.x + v1.y) * 0.25f;
        }
        __syncthreads();
        float g = 0.f, l = 0.f;
        for (int k = tid; k < 32 * 32; k += 256) {
            int y = k >> 5, x = k & 31;
            const float* u0 = &U[y * RS + x];
            const float* v0 = &V[y * RS + x];
            float a00 = u0[0],      a01 = u0[1],          a02 = u0[2];
            float a10 = u0[RS],     a11 = u0[RS + 1],     a12 = u0[RS + 2];
            float a20 = u0[2 * RS], a21 = u0[2 * RS + 1], a22 = u0[2 * RS + 2];
            float c00 = v0[0],      c01 = v0[1],          c02 = v0[2];
            float c10 = v0[RS],     c11 = v0[RS + 1],     c12 = v0[RS + 2];
            float c20 = v0[2 * RS], c21 = v0[2 * RS + 1], c22 = v0[2 * RS + 2];
            float gxu = (a02 - a00) + 2.f * (a12 - a10) + (a22 - a20);
            float gyu = (a20 - a00) + 2.f * (a21 - a01) + (a22 - a02);
            float gxv = (c02 - c00) + 2.f * (c12 - c10) + (c22 - c20);
            float gyv = (c20 - c00) + 2.f * (c21 - c01) + (c22 - c02);
            float lpu = a01 + a10 - 4.f * a11 + a12 + a21;
            float lpv = c01 + c10 - 4.f * c11 + c12 + c21;
            float grad = gxu * gxu + gyu * gyu + gxv * gxv + gyv * gyv;
            float lap = lpu * lpu + lpv * lpv;
            g += fminf(grad, 100.f);
            l += fminf(lap, 100.f);
        }
        red[tid] = g;
        __syncthreads();
        for (int s = 128; s > 0; s >>= 1) { if (tid < s) red[tid] += red[tid + s]; __syncthreads(); }
        if (tid == 0) pgrad[rb] = (double)red[0];
        __syncthreads();
        red[tid] = l;
        __syncthreads();
        for (int s = 128; s > 0; s >>= 1) { if (tid < s) red[tid] += red[tid + s]; __syncthreads(); }
        if (tid == 0) plap[rb] = (double)red[0];
    }
}

// ONE block: per-batch NMI from hist partials + all partial-sum reductions + final combine
__global__ void nmi_final_kernel(const unsigned* __restrict__ hist_part,
                                 const double* __restrict__ pmind,
                                 const double* __restrict__ pgrad,
                                 const double* __restrict__ plap,
                                 float* __restrict__ out) {
    int t = threadIdx.x;  // 256
    __shared__ float p[256];
    __shared__ float xh[16], yh[16];
    __shared__ float red[256];
    __shared__ double redd[256];
    __shared__ float nmi_acc_s;
    if (t == 0) nmi_acc_s = 0.f;
    __syncthreads();

    for (int b = 0; b < BATCH; b++) {
        unsigned hv = 0;
        const unsigned* hp = hist_part + (size_t)b * 256 * 256 + t;   // 256 blocks/batch
        for (int i = 0; i < 256; i++) hv += hp[i * 256];
        float pv = (float)hv / 65536.0f;  // sum+1e-10 == 65536 in fp32
        p[t] = pv;
        __syncthreads();
        if (t < 16) {
            float s = 0.f;
            for (int j = 0; j < 16; j++) s += p[t * 16 + j];
            xh[t] = s;
        } else if (t < 32) {
            int j = t - 16;
            float s = 0.f;
            for (int i = 0; i < 16; i++) s += p[i * 16 + j];
            yh[j] = s;
        }
        __syncthreads();
        const float eps = 1e-5f;
        int i = t >> 4, j = t & 15;
        float h = pv + eps;
        float mi_term = h * (logf(h) - logf((xh[i] + eps) * (yh[j] + eps)));
        red[t] = mi_term;
        __syncthreads();
        for (int s = 128; s > 0; s >>= 1) { if (t < s) red[t] += red[t + s]; __syncthreads(); }
        float mi = red[0];
        __syncthreads();
        float e_term = 0.f;
        if (t < 16) { float xe = xh[t] + eps; e_term = -xe * logf(xe); }
        else if (t < 32) { float ye = yh[t - 16] + eps; e_term = -ye * logf(ye); }
        red[t] = e_term;
        __syncthreads();
        for (int s = 128; s > 0; s >>= 1) { if (t < s) red[t] += red[t + s]; __syncthreads(); }
        if (t == 0) {
            float se = red[0];  // hx + hy
            float nmi = (se < 1e-10f) ? 0.f : 2.f * mi / se;
            nmi_acc_s += fminf(fmaxf(nmi, -1.f), 1.f);
        }
        __syncthreads();
    }

    double sm = 0.0;
    for (int i = t; i < NMIND_BLOCKS; i += 256) sm += pmind[i];
    double sg = 0.0, sl = 0.0;
    for (int i = t; i < NREG_BLOCKS; i += 256) { sg += pgrad[i]; sl += plap[i]; }
    redd[t] = sm;
    __syncthreads();
    for (int s = 128; s > 0; s >>= 1) { if (t < s) redd[t] += redd[t + s]; __syncthreads(); }
    double mind_sum = redd[0];
    __syncthreads();
    redd[t] = sg;
    __syncthreads();
    for (int s = 128; s > 0; s >>= 1) { if (t < s) redd[t] += redd[t + s]; __syncthreads(); }
    double grad_sum = redd[0];
    __syncthreads();
    redd[t] = sl;
    __syncthreads();
    for (int s = 128; s > 0; s >>= 1) { if (t < s) redd[t] += redd[t + s]; __syncthreads(); }
    double lap_sum = redd[0];
    if (t == 0) {
        float s = nmi_acc_s / (float)BATCH;
        s = fminf(fmaxf(s, -1.f), 1.f);
        double mi_loss = -(double)s;
        double mind_mean = mind_sum / (64.0 * (double)PLANE_F);
        double reg = grad_sum / (double)(BATCH * PLANE_S) + lap_sum / (double)(BATCH * PLANE_S);
        out[0] = (float)(mi_loss + 5.0 * mind_mean + 0.1 * reg);
    }
}

extern "C" void kernel_launch(void* const* d_in, const int* in_sizes, int n_in,
                              void* d_out, int out_size, void* d_ws, size_t ws_size,
                              hipStream_t stream) {
    const float* fixed = (const float*)d_in[0];
    const float* moved = (const float*)d_in[1];
    const float* flow  = (const float*)d_in[2];
    float* out = (float*)d_out;
    char* ws = (char*)d_ws;

    unsigned* hist_part = (unsigned*)(ws + OFF_HISTP);
    double*   pmind     = (double*)(ws + OFF_PMIND);
    double*   pgrad     = (double*)(ws + OFF_PGRAD);
    double*   plap      = (double*)(ws + OFF_PLAP);

    fused_main_kernel<<<TOTAL_BLOCKS, 256, 0, stream>>>(
        fixed, moved, flow, hist_part, pmind, pgrad, plap);
    nmi_final_kernel<<<1, 256, 0, stream>>>(hist_part, pmind, pgrad, plap, out);
}

// Round 9
// 117.094 us; speedup vs baseline: 2.5897x; 1.5392x over previous
//
#include <hip/hip_runtime.h>
#include <cmath>

// Problem constants
#define BATCH 8
#define HF 512
#define WF 512
#define HS 256
#define WS 256
#define PLANE_S (HS * WS)   // 65536
#define PLANE_F (HF * WF)   // 262144

#define NMIND_BLOCKS 2048   // 16x16 tiles (32x32 output each) x 8 batches
#define NREG_BLOCKS  512    // 8x8 tiles (32x32 pooled each) x 8 batches
#define TOTAL_BLOCKS (NMIND_BLOCKS + NREG_BLOCKS)

// Workspace layout (bytes); hist zeroed by an 8 KB hipMemsetAsync
#define OFF_HIST  0                              // 8*256 u32 = 8192 B
#define OFF_PMIND 8192                           // 2048 doubles
#define OFF_PGRAD (OFF_PMIND + NMIND_BLOCKS * 8) // 512 doubles
#define OFF_PLAP  (OFF_PGRAD + NREG_BLOCKS * 8)  // 512 doubles

// mind-role geometry (32x32 output tile)
#define IMG_R 23   // pooled img patch (halo: +3 left/top, +19 span)
#define IMG_S 25
#define T_R 20
#define T_S 21
#define V_R 18     // diff/var patch
#define V_S 19
#define VP  (V_R * V_S)   // 342, diff plane stride (float2 units for packed pairs)

// reg-role geometry (32x32 pooled tile)
#define RP 34
#define RS 35

__device__ __forceinline__ int clampi(int v, int lo, int hi) {
    return v < lo ? lo : (v > hi ? hi : v);
}

__device__ __forceinline__ int bin_of(float x) {
    float v = (x + 1.0f) * 0.5f;
    v = fminf(fmaxf(v, 0.001f), 0.999f);
    float t = v * 16.0f;            // exact (power-of-2 scale)
    float ft = floorf(t);
    int c = (int)ft + ((t > ft) ? 1 : 0);   // searchsorted-left count of grid < v
    int b = c - 1;
    return b < 0 ? 0 : (b > 15 ? 15 : b);
}

// ONE compute dispatch. Blocks 0..2047: MIND role. Blocks 2048..2559: reg role.
// Histogram: LDS-accumulated per block, then fire-and-forget u32 global atomics
// into 8x256 bins (native single-instruction atomics — cheap; R5-validated).
// NO device-scope fences (R6's per-block L2-writeback disaster).
__global__ __launch_bounds__(256, 6) void fused_main_kernel(
    const float* __restrict__ fixed, const float* __restrict__ moved,
    const float* __restrict__ flow,
    unsigned* __restrict__ hist,
    double* __restrict__ pmind, double* __restrict__ pgrad, double* __restrict__ plap)
{
    __shared__ float S[4570];       // 18.3 KB, shared by both roles
    __shared__ unsigned lh[256];
    __shared__ float red[256];
    int tid = threadIdx.x;

    if (blockIdx.x < NMIND_BLOCKS) {
        // ---------------- MIND role ----------------
        int mb = blockIdx.x;                 // 0..2047
        int b = mb >> 8, rem = mb & 255;
        int ty = rem >> 4, tx = rem & 15;
        const float FS = (float)(255.0 / 511.0);
        int Xb = tx * 32, Yb = ty * 32;
        int dbx = (int)((float)Xb * FS);     // min x0 over tile (fp32 mult is monotone)
        int dby = (int)((float)Yb * FS);
        int ibx = dbx - 3, iby = dby - 3;

        float* imgF = S;                     // 23*25 = 575
        float* imgM = S + 575;               // 575
        float* varF = S + 1150;              // 18*19 = 342
        float* varM = S + 1492;              // 342
        float2* diff2 = (float2*)(S + 1834); // 4 channel-pairs * 342 float2 = 2736 floats
        float* tF   = S + 1834;              // 20*21 = 420 (dead before diff written)
        float* tM   = tF + T_R * T_S;        // 420

        lh[tid] = 0u;
        __syncthreads();

        // ---- stage pooled F/M patches (clamp = edge-pad) + ::2,::2 histogram samples
        const float* fb = fixed + (size_t)b * PLANE_F;
        const float* mbp = moved + (size_t)b * PLANE_F;
        int oy0 = ty * 16, ox0 = tx * 16;    // owned pooled box (exact cover of 256x256)
        for (int i = tid; i < IMG_R * IMG_R; i += 256) {
            int r = i / IMG_R, c = i - r * IMG_R;
            int gy = iby + r, gx = ibx + c;
            int cy = clampi(gy, 0, HS - 1), cx = clampi(gx, 0, WS - 1);
            const float* fp = fb + (size_t)(cy * 2) * WF + (size_t)(cx * 2);
            const float* mp = mbp + (size_t)(cy * 2) * WF + (size_t)(cx * 2);
            float2 f0 = *(const float2*)fp;
            float2 f1 = *(const float2*)(fp + WF);
            float2 m0 = *(const float2*)mp;
            float2 m1 = *(const float2*)(mp + WF);
            imgF[r * IMG_S + c] = (f0.x + f0.y + f1.x + f1.y) * 0.25f;
            imgM[r * IMG_S + c] = (m0.x + m0.y + m1.x + m1.y) * 0.25f;
            if ((unsigned)(gy - oy0) < 16u && (unsigned)(gx - ox0) < 16u) {
                atomicAdd(&lh[bin_of(f0.x) * 16 + bin_of(m0.x)], 1u);   // LDS atomic
            }
        }
        __syncthreads();
        { // u32 global atomic, fire-and-forget (hist zeroed by host memset)
            unsigned v = lh[tid];
            if (v) atomicAdd(&hist[b * 256 + tid], v);
        }

        // ---- t = (img[q] - boxmean(img[q-2..q]))^2   [reference pad/slice quirk]
        for (int i = tid; i < T_R * T_R; i += 256) {
            int r = i / T_R, c = i - r * T_R;
            float sF = 0.f, sM = 0.f;
            #pragma unroll
            for (int dy = 0; dy < 3; dy++)
                #pragma unroll
                for (int dx = 0; dx < 3; dx++) {
                    sF += imgF[(r + dy) * IMG_S + c + dx];
                    sM += imgM[(r + dy) * IMG_S + c + dx];
                }
            float dF = imgF[(r + 2) * IMG_S + c + 2] - sF / 9.0f;
            float dM = imgM[(r + 2) * IMG_S + c + 2] - sM / 9.0f;
            tF[r * T_S + c] = dF * dF;
            tM[r * T_S + c] = dM * dM;
        }
        __syncthreads();

        // ---- var = max(box3x3(t)/9, 1e-4); keep in regs (t aliased by diff)
        float vFl[2], vMl[2];
        int vi[2];
        #pragma unroll
        for (int p = 0; p < 2; p++) {
            int i = tid + p * 256;
            vi[p] = -1;
            if (i < V_R * V_R) {
                int r = i / V_R, c = i - r * V_R;
                float sF = 0.f, sM = 0.f;
                #pragma unroll
                for (int dy = 0; dy < 3; dy++)
                    #pragma unroll
                    for (int dx = 0; dx < 3; dx++) {
                        sF += tF[(r + dy) * T_S + c + dx];
                        sM += tM[(r + dy) * T_S + c + dx];
                    }
                vFl[p] = fmaxf(sF / 9.0f, 1e-4f);
                vMl[p] = fmaxf(sM / 9.0f, 1e-4f);
                vi[p] = r * V_S + c;
            }
        }
        __syncthreads();
        #pragma unroll
        for (int p = 0; p < 2; p++) if (vi[p] >= 0) { varF[vi[p]] = vFl[p]; varM[vi[p]] = vMl[p]; }
        __syncthreads();

        // ---- MIND + diff, channel-PAIR packed planes (float2): conflict-free b64
        for (int i = tid; i < V_R * V_R; i += 256) {
            int r = i / V_R, c = i - r * V_R;
            float cF = imgF[(r + 3) * IMG_S + c + 3];
            float cM = imgM[(r + 3) * IMG_S + c + 3];
            float dF2 = 2.f * varF[r * V_S + c] + 1e-6f;
            float dM2 = 2.f * varM[r * V_S + c] + 1e-6f;
            float eF[8], eM[8];
            float sF = 0.f, sM = 0.f;
            int ch = 0;
            #pragma unroll
            for (int ii = -1; ii <= 1; ii++) {
                #pragma unroll
                for (int jj = -1; jj <= 1; jj++) {
                    if (ii == 0 && jj == 0) continue;
                    float aF = cF - imgF[(r + 3 + 2 * jj) * IMG_S + (c + 3 + 2 * ii)];
                    float aM = cM - imgM[(r + 3 + 2 * jj) * IMG_S + (c + 3 + 2 * ii)];
                    float qF = fminf(aF * aF / dF2, 50.f);
                    float qM = fminf(aM * aM / dM2, 50.f);
                    float vF_ = __expf(-qF), vM_ = __expf(-qM);
                    eF[ch] = vF_; eM[ch] = vM_;
                    sF += vF_; sM += vM_;
                    ch++;
                }
            }
            float wF = 1.f / (sF + 1e-8f);
            float wM = 1.f / (sM + 1e-8f);
            int base = r * V_S + c;
            #pragma unroll
            for (int q2 = 0; q2 < 4; q2++) {
                float2 d;
                d.x = eF[2 * q2]     * wF - eM[2 * q2]     * wM;
                d.y = eF[2 * q2 + 1] * wF - eM[2 * q2 + 1] * wM;
                diff2[q2 * VP + base] = d;
            }
        }
        __syncthreads();

        // ---- bilinear align-corners upsample + sum|.| (exact reference association)
        float local = 0.f;
        for (int k = tid; k < 32 * 32; k += 256) {
            int dy = k >> 5, dx = k & 31;
            float py = (float)(Yb + dy) * FS;
            int y0 = (int)py; if (y0 > HS - 2) y0 = HS - 2;
            float fy = py - (float)y0;
            float px = (float)(Xb + dx) * FS;
            int x0 = (int)px; if (x0 > WS - 2) x0 = WS - 2;
            float fx = px - (float)x0;
            float omfy = 1.f - fy, omfx = 1.f - fx;
            int base = (y0 - dby) * V_S + (x0 - dbx);
            #pragma unroll
            for (int q2 = 0; q2 < 4; q2++) {
                const float2* pq = diff2 + q2 * VP + base;
                float2 p00 = pq[0], p01 = pq[1];
                float2 p10 = pq[V_S], p11 = pq[V_S + 1];
                float ax = p00.x * omfy + p10.x * fy;
                float bx = p01.x * omfy + p11.x * fy;
                local += fabsf(ax * omfx + bx * fx);
                float ay = p00.y * omfy + p10.y * fy;
                float by = p01.y * omfy + p11.y * fy;
                local += fabsf(ay * omfx + by * fx);
            }
        }
        red[tid] = local;
        __syncthreads();
        for (int s = 128; s > 0; s >>= 1) { if (tid < s) red[tid] += red[tid + s]; __syncthreads(); }
        if (tid == 0) pmind[mb] = (double)red[0];
    } else {
        // ---------------- reg role ----------------
        int rb = blockIdx.x - NMIND_BLOCKS;     // 0..511
        int b = rb >> 6, rem = rb & 63;
        int tyr = rem >> 3, txr = rem & 7;
        int y0p = tyr * 32, x0p = txr * 32;
        float* U = S;                 // 34*35 = 1190
        float* V = S + RP * RS;       // 1190
        const float* ur = flow + (size_t)(b * 2) * PLANE_F;
        const float* vr = ur + PLANE_F;
        for (int i = tid; i < RP * RP; i += 256) {
            int r = i / RP, c = i - r * RP;
            int gy = clampi(y0p - 1 + r, 0, HS - 1);
            int gx = clampi(x0p - 1 + c, 0, WS - 1);
            const float* uu = ur + (size_t)(gy * 2) * WF + (size_t)(gx * 2);
            const float* vv = vr + (size_t)(gy * 2) * WF + (size_t)(gx * 2);
            float2 u0 = *(const float2*)uu, u1 = *(const float2*)(uu + WF);
            float2 v0 = *(const float2*)vv, v1 = *(const float2*)(vv + WF);
            U[r * RS + c] = (u0.x + u0.y + u1.x + u1.y) * 0.25f;
            V[r * RS + c] = (v0.x + v0.y + v1.x + v1.y) * 0.25f;
        }
        __syncthreads();
        float g = 0.f, l = 0.f;
        for (int k = tid; k < 32 * 32; k += 256) {
            int y = k >> 5, x = k & 31;
            const float* u0 = &U[y * RS + x];
            const float* v0 = &V[y * RS + x];
            float a00 = u0[0],      a01 = u0[1],          a02 = u0[2];
            float a10 = u0[RS],     a11 = u0[RS + 1],     a12 = u0[RS + 2];
            float a20 = u0[2 * RS], a21 = u0[2 * RS + 1], a22 = u0[2 * RS + 2];
            float c00 = v0[0],      c01 = v0[1],          c02 = v0[2];
            float c10 = v0[RS],     c11 = v0[RS + 1],     c12 = v0[RS + 2];
            float c20 = v0[2 * RS], c21 = v0[2 * RS + 1], c22 = v0[2 * RS + 2];
            float gxu = (a02 - a00) + 2.f * (a12 - a10) + (a22 - a20);
            float gyu = (a20 - a00) + 2.f * (a21 - a01) + (a22 - a02);
            float gxv = (c02 - c00) + 2.f * (c12 - c10) + (c22 - c20);
            float gyv = (c20 - c00) + 2.f * (c21 - c01) + (c22 - c02);
            float lpu = a01 + a10 - 4.f * a11 + a12 + a21;
            float lpv = c01 + c10 - 4.f * c11 + c12 + c21;
            float grad = gxu * gxu + gyu * gyu + gxv * gxv + gyv * gyv;
            float lap = lpu * lpu + lpv * lpv;
            g += fminf(grad, 100.f);
            l += fminf(lap, 100.f);
        }
        red[tid] = g;
        __syncthreads();
        for (int s = 128; s > 0; s >>= 1) { if (tid < s) red[tid] += red[tid + s]; __syncthreads(); }
        if (tid == 0) pgrad[rb] = (double)red[0];
        __syncthreads();
        red[tid] = l;
        __syncthreads();
        for (int s = 128; s > 0; s >>= 1) { if (tid < s) red[tid] += red[tid + s]; __syncthreads(); }
        if (tid == 0) plap[rb] = (double)red[0];
    }
}

// ONE block: per-batch NMI from the 8x256 hist + partial-sum reductions + final combine
__global__ void nmi_final_kernel(const unsigned* __restrict__ hist,
                                 const double* __restrict__ pmind,
                                 const double* __restrict__ pgrad,
                                 const double* __restrict__ plap,
                                 float* __restrict__ out) {
    int t = threadIdx.x;  // 256
    __shared__ float p[256];
    __shared__ float xh[16], yh[16];
    __shared__ float red[256];
    __shared__ double redd[256];
    __shared__ float nmi_acc_s;
    if (t == 0) nmi_acc_s = 0.f;
    __syncthreads();

    for (int b = 0; b < BATCH; b++) {
        float pv = (float)hist[b * 256 + t] / 65536.0f;  // sum+1e-10 == 65536 in fp32
        p[t] = pv;
        __syncthreads();
        if (t < 16) {
            float s = 0.f;
            for (int j = 0; j < 16; j++) s += p[t * 16 + j];
            xh[t] = s;
        } else if (t < 32) {
            int j = t - 16;
            float s = 0.f;
            for (int i = 0; i < 16; i++) s += p[i * 16 + j];
            yh[j] = s;
        }
        __syncthreads();
        const float eps = 1e-5f;
        int i = t >> 4, j = t & 15;
        float h = pv + eps;
        float mi_term = h * (logf(h) - logf((xh[i] + eps) * (yh[j] + eps)));
        red[t] = mi_term;
        __syncthreads();
        for (int s = 128; s > 0; s >>= 1) { if (t < s) red[t] += red[t + s]; __syncthreads(); }
        float mi = red[0];
        __syncthreads();
        float e_term = 0.f;
        if (t < 16) { float xe = xh[t] + eps; e_term = -xe * logf(xe); }
        else if (t < 32) { float ye = yh[t - 16] + eps; e_term = -ye * logf(ye); }
        red[t] = e_term;
        __syncthreads();
        for (int s = 128; s > 0; s >>= 1) { if (t < s) red[t] += red[t + s]; __syncthreads(); }
        if (t == 0) {
            float se = red[0];  // hx + hy
            float nmi = (se < 1e-10f) ? 0.f : 2.f * mi / se;
            nmi_acc_s += fminf(fmaxf(nmi, -1.f), 1.f);
        }
        __syncthreads();
    }

    double sm = 0.0;
    for (int i = t; i < NMIND_BLOCKS; i += 256) sm += pmind[i];
    double sg = 0.0, sl = 0.0;
    for (int i = t; i < NREG_BLOCKS; i += 256) { sg += pgrad[i]; sl += plap[i]; }
    redd[t] = sm;
    __syncthreads();
    for (int s = 128; s > 0; s >>= 1) { if (t < s) redd[t] += redd[t + s]; __syncthreads(); }
    double mind_sum = redd[0];
    __syncthreads();
    redd[t] = sg;
    __syncthreads();
    for (int s = 128; s > 0; s >>= 1) { if (t < s) redd[t] += redd[t + s]; __syncthreads(); }
    double grad_sum = redd[0];
    __syncthreads();
    redd[t] = sl;
    __syncthreads();
    for (int s = 128; s > 0; s >>= 1) { if (t < s) redd[t] += redd[t + s]; __syncthreads(); }
    double lap_sum = redd[0];
    if (t == 0) {
        float s = nmi_acc_s / (float)BATCH;
        s = fminf(fmaxf(s, -1.f), 1.f);
        double mi_loss = -(double)s;
        double mind_mean = mind_sum / (64.0 * (double)PLANE_F);
        double reg = grad_sum / (double)(BATCH * PLANE_S) + lap_sum / (double)(BATCH * PLANE_S);
        out[0] = (float)(mi_loss + 5.0 * mind_mean + 0.1 * reg);
    }
}

extern "C" void kernel_launch(void* const* d_in, const int* in_sizes, int n_in,
                              void* d_out, int out_size, void* d_ws, size_t ws_size,
                              hipStream_t stream) {
    const float* fixed = (const float*)d_in[0];
    const float* moved = (const float*)d_in[1];
    const float* flow  = (const float*)d_in[2];
    float* out = (float*)d_out;
    char* ws = (char*)d_ws;

    unsigned* hist  = (unsigned*)(ws + OFF_HIST);
    double*   pmind = (double*)(ws + OFF_PMIND);
    double*   pgrad = (double*)(ws + OFF_PGRAD);
    double*   plap  = (double*)(ws + OFF_PLAP);

    // zero the 8 KB histogram (capturable async memset)
    hipMemsetAsync(ws + OFF_HIST, 0, OFF_PMIND, stream);

    fused_main_kernel<<<TOTAL_BLOCKS, 256, 0, stream>>>(
        fixed, moved, flow, hist, pmind, pgrad, plap);
    nmi_final_kernel<<<1, 256, 0, stream>>>(hist, pmind, pgrad, plap, out);
}